// Round 1
// baseline (101.152 us; speedup 1.0000x reference)
//
#include <hip/hip_runtime.h>

typedef _Float16 half2v __attribute__((ext_vector_type(2)));
typedef _Float16 half8  __attribute__((ext_vector_type(8)));
typedef float    floatx4 __attribute__((ext_vector_type(4)));

#define M_DIM 64
#define K_DIM 8192
#define N_DIM 8192
#define NT 64
#define KSPLIT 4
// K-chunk per wave = K_DIM / (KSPLIT*4) = 512

// Pre-pass: x fp32 [64][8192] -> fp16 in ws, with per-8 k-permutation
// sigma = (0,4,1,5,2,6,3,7) to match the nibble-unpack order of B.
__global__ __launch_bounds__(256) void permute_x_kernel(
        const float* __restrict__ x, _Float16* __restrict__ xp) {
    int t = blockIdx.x * 256 + threadIdx.x;          // word index, M*K/8 total
    const float* src = x + (size_t)t * 8;
    float4 a = *(const float4*)(src);
    float4 b = *(const float4*)(src + 4);
    union { _Float16 h[8]; float4 f; } u;
    u.h[0] = (_Float16)a.x; u.h[1] = (_Float16)b.x;
    u.h[2] = (_Float16)a.y; u.h[3] = (_Float16)b.y;
    u.h[4] = (_Float16)a.z; u.h[5] = (_Float16)b.z;
    u.h[6] = (_Float16)a.w; u.h[7] = (_Float16)b.w;
    *(float4*)(xp + (size_t)t * 8) = u.f;
}

__device__ __forceinline__ half2v dq_pair(unsigned int bits, half2v sub, half2v sc) {
    union { unsigned int u; half2v h; } cv;
    cv.u = bits;
    return (cv.h - sub) * sc;      // v_pk_add_f16 + v_pk_mul_f16
}

__global__ __launch_bounds__(256, 2) void machete_mm_kernel(
        const _Float16* __restrict__ xp,
        const unsigned int* __restrict__ Bq,
        const float* __restrict__ s,
        float* __restrict__ out) {
    __shared__ float red[4][M_DIM][NT];              // 64 KB

    const int tid  = threadIdx.x;
    const int w    = tid >> 6;                       // wave 0..3 (splits K)
    const int lane = tid & 63;
    const int c    = lane & 15;                      // mfma row/col within tile
    const int q    = lane >> 4;                      // quad: k sub-range
    const int n0   = blockIdx.x * NT;
    const int ci   = blockIdx.y * 4 + w;             // k-chunk 0..15
    const int kb   = ci * (K_DIM / (KSPLIT * 4));    // *512

    const int ncol = n0 + 4 * c;                     // 4 consecutive cols -> 4 tiles

    floatx4 acc[4][4];
    #pragma unroll
    for (int i = 0; i < 4; ++i)
        #pragma unroll
        for (int j = 0; j < 4; ++j) acc[i][j] = (floatx4)0.0f;

    const unsigned int* bptr = Bq + (size_t)((kb >> 3) + q) * N_DIM + ncol;
    const _Float16*     aptr = xp + (size_t)c * K_DIM + kb + q * 8;

    const half2v c1032 = { (_Float16)1032.0f, (_Float16)1032.0f };

    #pragma unroll
    for (int g = 0; g < 4; ++g) {                    // scale groups (128 k each)
        const int gg = (kb >> 7) + g;
        const float4 s4 = *(const float4*)(s + (size_t)gg * N_DIM + ncol);
        half2v s2[4];
        s2[0] = (half2v){ (_Float16)s4.x, (_Float16)s4.x };
        s2[1] = (half2v){ (_Float16)s4.y, (_Float16)s4.y };
        s2[2] = (half2v){ (_Float16)s4.z, (_Float16)s4.z };
        s2[3] = (half2v){ (_Float16)s4.w, (_Float16)s4.w };

        #pragma unroll
        for (int st = 0; st < 4; ++st) {             // K-steps of 32
            half8 afr[4];
            #pragma unroll
            for (int mt = 0; mt < 4; ++mt)
                afr[mt] = *(const half8*)(aptr + (size_t)mt * 16 * K_DIM);

            union { uint4 v; unsigned int a[4]; } bv;
            bv.v = *(const uint4*)bptr;

            #pragma unroll
            for (int t = 0; t < 4; ++t) {
                const unsigned int wd = bv.a[t];
                union { half2v h2[4]; half8 h8; } bf;
                bf.h2[0] = dq_pair(( wd        & 0x000F000Fu) | 0x64006400u, c1032, s2[t]);
                bf.h2[1] = dq_pair(((wd >> 4)  & 0x000F000Fu) | 0x64006400u, c1032, s2[t]);
                bf.h2[2] = dq_pair(((wd >> 8)  & 0x000F000Fu) | 0x64006400u, c1032, s2[t]);
                bf.h2[3] = dq_pair(((wd >> 12) & 0x000F000Fu) | 0x64006400u, c1032, s2[t]);
                #pragma unroll
                for (int mt = 0; mt < 4; ++mt)
                    acc[mt][t] = __builtin_amdgcn_mfma_f32_16x16x32_f16(
                        afr[mt], bf.h8, acc[mt][t], 0, 0, 0);
            }
            aptr += 32;
            bptr += (size_t)4 * N_DIM;
        }
    }

    // cross-wave (K-split) reduction via LDS, then one atomicAdd per output
    #pragma unroll
    for (int mt = 0; mt < 4; ++mt)
        #pragma unroll
        for (int t = 0; t < 4; ++t)
            #pragma unroll
            for (int r = 0; r < 4; ++r)
                red[w][mt * 16 + q * 4 + r][4 * c + t] = acc[mt][t][r];
    __syncthreads();

    #pragma unroll
    for (int i = 0; i < 16; ++i) {
        int idx = i * 256 + tid;
        int m = idx >> 6, nl = idx & 63;
        float v = red[0][m][nl] + red[1][m][nl] + red[2][m][nl] + red[3][m][nl];
        atomicAdd(out + (size_t)m * N_DIM + n0 + nl, v);
    }
}

extern "C" void kernel_launch(void* const* d_in, const int* in_sizes, int n_in,
                              void* d_out, int out_size, void* d_ws, size_t ws_size,
                              hipStream_t stream) {
    const float*        x  = (const float*)d_in[0];
    const unsigned int* Bq = (const unsigned int*)d_in[1];
    const float*        sc = (const float*)d_in[2];
    float* out    = (float*)d_out;
    _Float16* xp  = (_Float16*)d_ws;   // M*K*2 = 1 MB

    hipMemsetAsync(d_out, 0, (size_t)M_DIM * N_DIM * sizeof(float), stream);
    permute_x_kernel<<<dim3((M_DIM * K_DIM / 8) / 256), 256, 0, stream>>>(x, xp);
    machete_mm_kernel<<<dim3(N_DIM / NT, KSPLIT), 256, 0, stream>>>(xp, Bq, sc, out);
}